// Round 10
// baseline (161.757 us; speedup 1.0000x reference)
//
#include <hip/hip_runtime.h>
#include <cstdint>

typedef __attribute__((ext_vector_type(8))) short short8;
typedef __attribute__((ext_vector_type(4))) float f32x4;
typedef __attribute__((ext_vector_type(2))) float f32x2;

#define NE 128     // n_e (K)
#define RR 256     // RANK*RANK (N)
#define MT 32      // batch rows per block
#define JST 260    // jbuf per-matrix stride (words)

__device__ __forceinline__ float u2f(unsigned u) { return __builtin_bit_cast(float, u); }
__device__ __forceinline__ unsigned f2u(float f) { return __builtin_bit_cast(unsigned, f); }
__device__ __forceinline__ unsigned short f2bf(float x) {
  unsigned u = f2u(x);
  unsigned r = (u + 0x7FFFu + ((u >> 16) & 1u)) >> 16;
  return (unsigned short)r;
}
__device__ __forceinline__ float bf2f(unsigned short h) {
  return u2f(((unsigned)h) << 16);
}
__device__ __forceinline__ float bperm_f(int byteidx, float v) {
  return __builtin_bit_cast(float,
      __builtin_amdgcn_ds_bpermute(byteidx, __builtin_bit_cast(int, v)));
}
template<int CTRL>
__device__ __forceinline__ unsigned dpp_maxu(unsigned k) {
  unsigned o = (unsigned)__builtin_amdgcn_update_dpp(0, (int)k, CTRL, 0xF, 0xF, true);
  return o > k ? o : k;
}

// 3-way ROUND-TO-NEAREST split (R3/R4/R6-proven): x ~= h1+h2+h3, residual ~2^-27|x|.
__device__ __forceinline__ void split3(float x, unsigned short& a,
                                       unsigned short& b, unsigned short& c) {
  unsigned short h1 = f2bf(x);
  float r1 = x - bf2f(h1);
  unsigned short h2 = f2bf(r1);
  float r2 = r1 - bf2f(h2);
  a = h1; b = h2; c = f2bf(r2);
}

// ---- pre-kernel: 3-way split W (f32 [128][256]) -> h/m/l bf16, fragment-major
__global__ __launch_bounds__(256)
void wsplit3_kernel(const float* __restrict__ W,
                    unsigned short* __restrict__ wh,
                    unsigned short* __restrict__ wm,
                    unsigned short* __restrict__ wl) {
  int t = blockIdx.x * 256 + threadIdx.x;   // 0..32767
  int k = t >> 8, col = t & 255;
  unsigned short h1, h2, h3;
  split3(W[t], h1, h2, h3);
  int kt = k >> 5, klo = k & 31;
  int lane = ((klo >> 3) << 4) | (col & 15);
  int u = klo & 7;
  int ct = col >> 4;
  int e = ((kt * 16 + ct) * 64 + lane) * 8 + u;
  wh[e] = h1; wm[e] = h2; wl[e] = h3;
}

// ---- main fused kernel ----
// MT=32; waves partition COLUMNS. (256,3): budget 512/3~170 regs/wave so the
// LU working set (xp = 64 f32) stays in VGPRs (R9's plain bounds let the
// allocator clamp to 64 VGPR + AGPR-shuffle xp => +VALU on critical chains).
// R7 lesson: never request more waves than the live set can fit (4 => spill).
__global__ __launch_bounds__(256, 3)
void jastrow_mfma(const float* __restrict__ occ,
                  const unsigned short* __restrict__ wh,
                  const unsigned short* __restrict__ wm,
                  const unsigned short* __restrict__ wl,
                  const float* __restrict__ bias,
                  float* __restrict__ out, int B) {
  // phase A: occS f32 [32][132] = 16896 B (aliased); phase B: jbuf f32 [32][260] = 33280 B
  __shared__ __align__(16) char smem[MT * JST * 4];
  float* occS = (float*)smem;
  float* jbuf = (float*)smem;

  const int tid  = threadIdx.x;
  const int lane = tid & 63;
  const int wv   = tid >> 6;        // wave 0..3 = column quarter (64 cols each)
  const int l15  = lane & 15;
  const int lh   = lane >> 4;
  const long long b0 = (long long)blockIdx.x * MT;

  // ---- stage occ tile 32x128 f32 -> LDS [32][132] ----
  {
    const float* src = occ + b0 * NE;
    #pragma unroll
    for (int p = 0; p < 4; p++) {
      int flat = (tid + p * 256) * 4;
      int row = flat >> 7, e = flat & 127;
      f32x4 v = *(const f32x4*)(src + flat);
      *(f32x4*)(occS + row * 132 + e) = v;
    }
  }
  __syncthreads();

  // ---- GEMM: acc[rt][ct], 6-MFMA triple-split, A streamed per-kt ----
  f32x4 acc[2][4];
  #pragma unroll
  for (int ct = 0; ct < 4; ct++) {
    float bv = bias[(wv * 4 + ct) * 16 + l15];
    f32x4 a; a[0] = bv; a[1] = bv; a[2] = bv; a[3] = bv;
    acc[0][ct] = a; acc[1][ct] = a;
  }
  #pragma unroll
  for (int kt = 0; kt < 4; kt++) {
    // A fragments for this kt only (rows rt*16+l15, k = kt*32 + lh*8 + u)
    short8 Ah[2], Am[2], Al[2];
    #pragma unroll
    for (int rt = 0; rt < 2; rt++) {
      const float* p = occS + (rt * 16 + l15) * 132 + kt * 32 + lh * 8;
      f32x4 v0 = *(const f32x4*)p;
      f32x4 v1 = *(const f32x4*)(p + 4);
      float xs[8] = {v0[0], v0[1], v0[2], v0[3], v1[0], v1[1], v1[2], v1[3]};
      #pragma unroll
      for (int u = 0; u < 8; u++) {
        unsigned short h1, h2, h3;
        split3(xs[u], h1, h2, h3);
        Ah[rt][u] = (short)h1;
        Am[rt][u] = (short)h2;
        Al[rt][u] = (short)h3;
      }
    }
    #pragma unroll
    for (int ct = 0; ct < 4; ct++) {
      const int ctg = wv * 4 + ct;
      int fo = ((kt * 16 + ctg) * 64 + lane) * 8;
      short8 bh = *(const short8*)(wh + fo);
      short8 bm = *(const short8*)(wm + fo);
      short8 bl = *(const short8*)(wl + fo);
      #pragma unroll
      for (int rt = 0; rt < 2; rt++) {
        f32x4 c = acc[rt][ct];
        c = __builtin_amdgcn_mfma_f32_16x16x32_bf16(Ah[rt], bh, c, 0, 0, 0);
        c = __builtin_amdgcn_mfma_f32_16x16x32_bf16(Ah[rt], bm, c, 0, 0, 0);
        c = __builtin_amdgcn_mfma_f32_16x16x32_bf16(Am[rt], bh, c, 0, 0, 0);
        c = __builtin_amdgcn_mfma_f32_16x16x32_bf16(Am[rt], bm, c, 0, 0, 0);
        c = __builtin_amdgcn_mfma_f32_16x16x32_bf16(Ah[rt], bl, c, 0, 0, 0);
        c = __builtin_amdgcn_mfma_f32_16x16x32_bf16(Al[rt], bh, c, 0, 0, 0);
        acc[rt][ct] = c;
      }
    }
  }
  __syncthreads();   // all occS reads done; jbuf aliases occS

  // ---- all 4 waves write their column quarter of all 32 matrices ----
  #pragma unroll
  for (int ct = 0; ct < 4; ct++) {
    const int ctg = wv * 4 + ct;
    #pragma unroll
    for (int rt = 0; rt < 2; rt++) {
      #pragma unroll
      for (int i = 0; i < 4; i++) {
        int m = rt * 16 + lh * 4 + i;
        jbuf[m * JST + ctg * 16 + l15] = acc[rt][ct][i];
      }
    }
  }
  __syncthreads();

  // ---- waves 2,3 done; waves 0,1 LU 16 matrices each (L=4, R8-verbatim) ----
  if (wv >= 2) return;

  const int l4 = lane & 3;          // lane within matrix group
  const int g  = lane >> 2;         // group 0..15 in wave
  const int gm = wv * 16 + g;       // matrix 0..31
  #define XW(i, j) (xp[i][(j) >> 1][(j) & 1])

  f32x2 xp[4][8];                   // rows l4+4i, 8 column pairs
  #pragma unroll
  for (int i = 0; i < 4; i++) {
    #pragma unroll
    for (int c4 = 0; c4 < 4; c4++) {
      f32x4 v = *(const f32x4*)&jbuf[gm * JST + (l4 + 4 * i) * 16 + c4 * 4];
      f32x2 t0; t0[0] = v[0]; t0[1] = v[1];
      f32x2 t1; t1[0] = v[2]; t1[1] = v[3];
      xp[i][c4 * 2]     = t0;
      xp[i][c4 * 2 + 1] = t1;
    }
  }
  // A = I + j : diag col of row l4+4i is l4+4i
  #pragma unroll
  for (int i = 0; i < 4; i++) {
    xp[i][2*i][0]     += (l4 == 0) ? 1.0f : 0.0f;
    xp[i][2*i][1]     += (l4 == 1) ? 1.0f : 0.0f;
    xp[i][2*i + 1][0] += (l4 == 2) ? 1.0f : 0.0f;
    xp[i][2*i + 1][1] += (l4 == 3) ? 1.0f : 0.0f;
  }

  unsigned used = 0u;
  int par = 0;
  int esum = 0;
  float prodm = 1.0f;
  const int lbase = (lane & 60) << 2;   // quad base, byte index
  #pragma unroll
  for (int k = 0; k < 16; k++) {
    // packed argmax over 16 rows (4 local + quad DPP reduce)
    float xk[4];
    unsigned kmax = 0u;
    #pragma unroll
    for (int i = 0; i < 4; i++) {
      xk[i] = XW(i, k);
      bool act = ((used >> (l4 + 4 * i)) & 1u) == 0u;
      unsigned ab = f2u(fabsf(xk[i]));
      unsigned code = (unsigned)(15 - 4 * i) - (unsigned)l4;
      unsigned key = act ? ((ab & 0xFFFFFFE0u) | 0x10u | code) : 0u;
      kmax = key > kmax ? key : kmax;
    }
    kmax = dpp_maxu<0xB1>(kmax);   // quad_perm [1,0,3,2]
    kmax = dpp_maxu<0x4E>(kmax);   // quad_perm [2,3,0,1]
    const int p = 15 - (int)(kmax & 0xFu);
    const bool pb0 = (p & 4) != 0;   // owner row-slot bit0
    const bool pb1 = (p & 8) != 0;   // owner row-slot bit1
    const int bidx = lbase | ((p & 3) << 2);

    float s01 = pb0 ? XW(1, k) : XW(0, k);
    float s23 = pb0 ? XW(3, k) : XW(2, k);
    float piv = bperm_f(bidx, pb1 ? s23 : s01);

    int e; float mant = frexpf(piv, &e);
    prodm *= mant; esum += e;
    par ^= __popc(used & (0xFFFFFFFFu << (p + 1))) & 1;  // inversion parity
    used |= 1u << p;

    float rp = (piv != 0.0f) ? (1.0f / piv) : 0.0f;   // IEEE divide

    f32x2 mf[4];
    #pragma unroll
    for (int i = 0; i < 4; i++) {
      bool act = ((used >> (l4 + 4 * i)) & 1u) == 0u;  // post-update mask (owner frozen)
      float f = act ? xk[i] * rp : 0.0f;
      mf[i][0] = -f; mf[i][1] = -f;
    }
    #pragma unroll
    for (int jp = (k + 1) >> 1; jp < 8; jp++) {
      float a01 = pb0 ? XW(1, 2 * jp) : XW(0, 2 * jp);
      float a23 = pb0 ? XW(3, 2 * jp) : XW(2, 2 * jp);
      float t0 = bperm_f(bidx, pb1 ? a23 : a01);
      float b01 = pb0 ? XW(1, 2 * jp + 1) : XW(0, 2 * jp + 1);
      float b23 = pb0 ? XW(3, 2 * jp + 1) : XW(2, 2 * jp + 1);
      float t1 = bperm_f(bidx, pb1 ? b23 : b01);
      f32x2 tp; tp[0] = t0; tp[1] = t1;
      #pragma unroll
      for (int i = 0; i < 4; i++)
        xp[i][jp] = __builtin_elementwise_fma(tp, mf[i], xp[i][jp]);
    }
  }
  if (l4 == 0) {
    float la = (__log2f(fabsf(prodm)) + (float)esum) * 0.6931471805599453f;
    int neg = (prodm < 0.0f) ? 1 : 0;
    float sg = (prodm == 0.0f) ? 0.0f : (((neg ^ par) != 0) ? -1.0f : 1.0f);
    long long b = b0 + gm;
    out[b] = sg;
    out[(long long)B + b] = la;
  }
  #undef XW
}

extern "C" void kernel_launch(void* const* d_in, const int* in_sizes, int n_in,
                              void* d_out, int out_size, void* d_ws, size_t ws_size,
                              hipStream_t stream) {
  const float* occ  = (const float*)d_in[0];
  const float* Wg   = (const float*)d_in[1];
  const float* bias = (const float*)d_in[2];
  float* out = (float*)d_out;
  const int B = in_sizes[0] / NE;          // 262144
  unsigned short* wh = (unsigned short*)d_ws;
  unsigned short* wm = wh + NE * RR;
  unsigned short* wl = wm + NE * RR;       // 196608 B total in d_ws

  hipLaunchKernelGGL(wsplit3_kernel, dim3(NE * RR / 256), dim3(256), 0, stream,
                     Wg, wh, wm, wl);
  hipLaunchKernelGGL(jastrow_mfma, dim3(B / MT), dim3(256), 0, stream,
                     occ, wh, wm, wl, bias, out, B);
}

// Round 11
// 141.669 us; speedup vs baseline: 1.1418x; 1.1418x over previous
//
#include <hip/hip_runtime.h>
#include <cstdint>

typedef __attribute__((ext_vector_type(8))) short short8;
typedef __attribute__((ext_vector_type(4))) float f32x4;
typedef __attribute__((ext_vector_type(2))) float f32x2;
typedef __attribute__((ext_vector_type(4))) unsigned uint32x4;

#define NE 128     // n_e (K)
#define RR 256     // RANK*RANK (N)
#define MT 64      // batch rows per block
#define JST 260    // jbuf per-matrix stride (words)

__device__ __forceinline__ float u2f(unsigned u) { return __builtin_bit_cast(float, u); }
__device__ __forceinline__ unsigned f2u(float f) { return __builtin_bit_cast(unsigned, f); }
__device__ __forceinline__ unsigned short f2bf(float x) {
  unsigned u = f2u(x);
  unsigned r = (u + 0x7FFFu + ((u >> 16) & 1u)) >> 16;
  return (unsigned short)r;
}
__device__ __forceinline__ float bf2f(unsigned short h) {
  return u2f(((unsigned)h) << 16);
}
__device__ __forceinline__ float bperm_f(int byteidx, float v) {
  return __builtin_bit_cast(float,
      __builtin_amdgcn_ds_bpermute(byteidx, __builtin_bit_cast(int, v)));
}
template<int CTRL>
__device__ __forceinline__ unsigned dpp_maxu(unsigned k) {
  unsigned o = (unsigned)__builtin_amdgcn_update_dpp(0, (int)k, CTRL, 0xF, 0xF, true);
  return o > k ? o : k;
}
// HW packed f32->bf16 RNE convert (gfx950): dst.lo16=bf(lo), dst.hi16=bf(hi)
__device__ __forceinline__ unsigned cvt_pk_bf16(float lo, float hi) {
  unsigned r;
  asm("v_cvt_pk_bf16_f32 %0, %1, %2" : "=v"(r) : "v"(lo), "v"(hi));
  return r;
}

// scalar 3-way RNE split (pre-kernel only; R3/R4/R6-proven numerics)
__device__ __forceinline__ void split3(float x, unsigned short& a,
                                       unsigned short& b, unsigned short& c) {
  unsigned short h1 = f2bf(x);
  float r1 = x - bf2f(h1);
  unsigned short h2 = f2bf(r1);
  float r2 = r1 - bf2f(h2);
  a = h1; b = h2; c = f2bf(r2);
}

// ---- pre-kernel: 3-way split W (f32 [128][256]) -> h/m/l bf16, fragment-major
__global__ __launch_bounds__(256)
void wsplit3_kernel(const float* __restrict__ W,
                    unsigned short* __restrict__ wh,
                    unsigned short* __restrict__ wm,
                    unsigned short* __restrict__ wl) {
  int t = blockIdx.x * 256 + threadIdx.x;   // 0..32767
  int k = t >> 8, col = t & 255;
  unsigned short h1, h2, h3;
  split3(W[t], h1, h2, h3);
  int kt = k >> 5, klo = k & 31;
  int lane = ((klo >> 3) << 4) | (col & 15);
  int u = klo & 7;
  int ct = col >> 4;
  int e = ((kt * 16 + ct) * 64 + lane) * 8 + u;
  wh[e] = h1; wm[e] = h2; wl[e] = h3;
}

// ---- main fused kernel ----
// R8 base (144us proven). (256,2): R7/R9/R10 showed any tighter bound makes the
// allocator spill/AGPR-shuffle the LU set. Change vs R8: A-split via
// v_cvt_pk_bf16_f32 (5.5 ops/value vs ~16) — numerics bit-identical (RNE).
__global__ __launch_bounds__(256, 2)
void jastrow_mfma(const float* __restrict__ occ,
                  const unsigned short* __restrict__ wh,
                  const unsigned short* __restrict__ wm,
                  const unsigned short* __restrict__ wl,
                  const float* __restrict__ bias,
                  float* __restrict__ out, int B) {
  // phase A: occS f32 [64][132] = 33792 B (aliased); phase B: jbuf f32 [64][260] = 66560 B
  __shared__ __align__(16) char smem[MT * JST * 4];
  float* occS = (float*)smem;
  float* jbuf = (float*)smem;

  const int tid  = threadIdx.x;
  const int lane = tid & 63;
  const int wv   = tid >> 6;        // wave 0..3
  const int wr   = wv >> 1;         // row half (32 rows)
  const int wc   = wv & 1;          // col half (128 cols)
  const int l15  = lane & 15;
  const int lh   = lane >> 4;
  const long long b0 = (long long)blockIdx.x * MT;

  // ---- stage occ tile 64x128 f32 -> LDS [64][132] ----
  {
    const float* src = occ + b0 * NE;
    #pragma unroll
    for (int p = 0; p < 8; p++) {
      int flat = (tid + p * 256) * 4;
      int row = flat >> 7, e = flat & 127;
      f32x4 v = *(const f32x4*)(src + flat);
      *(f32x4*)(occS + row * 132 + e) = v;
    }
  }
  __syncthreads();

  // ---- A fragments: 3-way bf16 split via v_cvt_pk_bf16_f32 ----
  short8 Ah[2][4], Am[2][4], Al[2][4];
  #pragma unroll
  for (int rt = 0; rt < 2; rt++) {
    #pragma unroll
    for (int kt = 0; kt < 4; kt++) {
      const float* p = occS + (wr * 32 + rt * 16 + l15) * 132 + kt * 32 + lh * 8;
      f32x4 v0 = *(const f32x4*)p;
      f32x4 v1 = *(const f32x4*)(p + 4);
      float xs[8] = {v0[0], v0[1], v0[2], v0[3], v1[0], v1[1], v1[2], v1[3]};
      uint32x4 ph, pm, pl;
      #pragma unroll
      for (int q = 0; q < 4; q++) {
        float x0 = xs[2*q], x1 = xs[2*q+1];
        unsigned h = cvt_pk_bf16(x0, x1);
        float r0 = x0 - u2f(h << 16);
        float r1 = x1 - u2f(h & 0xFFFF0000u);
        unsigned m = cvt_pk_bf16(r0, r1);
        float s0 = r0 - u2f(m << 16);
        float s1 = r1 - u2f(m & 0xFFFF0000u);
        unsigned l = cvt_pk_bf16(s0, s1);
        ph[q] = h; pm[q] = m; pl[q] = l;
      }
      Ah[rt][kt] = __builtin_bit_cast(short8, ph);
      Am[rt][kt] = __builtin_bit_cast(short8, pm);
      Al[rt][kt] = __builtin_bit_cast(short8, pl);
    }
  }
  __syncthreads();   // all occS reads done; jbuf may be written after this

  // ---- GEMM: 6-MFMA triple-split ----
  f32x4 acc[2][8];
  #pragma unroll
  for (int ct = 0; ct < 8; ct++) {
    float bv = bias[(wc * 8 + ct) * 16 + l15];
    f32x4 a; a[0] = bv; a[1] = bv; a[2] = bv; a[3] = bv;
    acc[0][ct] = a; acc[1][ct] = a;
  }
  #pragma unroll
  for (int kt = 0; kt < 4; kt++) {
    #pragma unroll
    for (int ct = 0; ct < 8; ct++) {
      const int ctg = wc * 8 + ct;
      int fo = ((kt * 16 + ctg) * 64 + lane) * 8;
      short8 bh = *(const short8*)(wh + fo);
      short8 bm = *(const short8*)(wm + fo);
      short8 bl = *(const short8*)(wl + fo);
      #pragma unroll
      for (int rt = 0; rt < 2; rt++) {
        f32x4 c = acc[rt][ct];
        c = __builtin_amdgcn_mfma_f32_16x16x32_bf16(Ah[rt][kt], bh, c, 0, 0, 0);
        c = __builtin_amdgcn_mfma_f32_16x16x32_bf16(Ah[rt][kt], bm, c, 0, 0, 0);
        c = __builtin_amdgcn_mfma_f32_16x16x32_bf16(Am[rt][kt], bh, c, 0, 0, 0);
        c = __builtin_amdgcn_mfma_f32_16x16x32_bf16(Am[rt][kt], bm, c, 0, 0, 0);
        c = __builtin_amdgcn_mfma_f32_16x16x32_bf16(Ah[rt][kt], bl, c, 0, 0, 0);
        c = __builtin_amdgcn_mfma_f32_16x16x32_bf16(Al[rt][kt], bh, c, 0, 0, 0);
        acc[rt][ct] = c;
      }
    }
  }

  // ---- single phase: ALL waves write all 64 matrices, then ALL waves LU ----
  #pragma unroll
  for (int ct = 0; ct < 8; ct++) {
    const int ctg = wc * 8 + ct;
    #pragma unroll
    for (int rt = 0; rt < 2; rt++) {
      #pragma unroll
      for (int i = 0; i < 4; i++) {
        int m = wr * 32 + rt * 16 + lh * 4 + i;
        jbuf[m * JST + ctg * 16 + l15] = acc[rt][ct][i];
      }
    }
  }
  __syncthreads();

  // ---- L=4 LU, 16 matrices per wave, all 4 waves active ----
  const int l4 = lane & 3;          // lane within matrix group
  const int g  = lane >> 2;         // group 0..15 in wave
  const int gm = wv * 16 + g;       // matrix 0..63
  #define XW(i, j) (xp[i][(j) >> 1][(j) & 1])

  f32x2 xp[4][8];                   // rows l4+4i, 8 column pairs
  #pragma unroll
  for (int i = 0; i < 4; i++) {
    #pragma unroll
    for (int c4 = 0; c4 < 4; c4++) {
      f32x4 v = *(const f32x4*)&jbuf[gm * JST + (l4 + 4 * i) * 16 + c4 * 4];
      f32x2 t0; t0[0] = v[0]; t0[1] = v[1];
      f32x2 t1; t1[0] = v[2]; t1[1] = v[3];
      xp[i][c4 * 2]     = t0;
      xp[i][c4 * 2 + 1] = t1;
    }
  }
  // A = I + j : diag col of row l4+4i is l4+4i
  #pragma unroll
  for (int i = 0; i < 4; i++) {
    xp[i][2*i][0]     += (l4 == 0) ? 1.0f : 0.0f;
    xp[i][2*i][1]     += (l4 == 1) ? 1.0f : 0.0f;
    xp[i][2*i + 1][0] += (l4 == 2) ? 1.0f : 0.0f;
    xp[i][2*i + 1][1] += (l4 == 3) ? 1.0f : 0.0f;
  }

  unsigned used = 0u;
  int par = 0;
  int esum = 0;
  float prodm = 1.0f;
  const int lbase = (lane & 60) << 2;   // quad base, byte index
  #pragma unroll
  for (int k = 0; k < 16; k++) {
    // packed argmax over 16 rows (4 local + quad DPP reduce)
    float xk[4];
    unsigned kmax = 0u;
    #pragma unroll
    for (int i = 0; i < 4; i++) {
      xk[i] = XW(i, k);
      bool act = ((used >> (l4 + 4 * i)) & 1u) == 0u;
      unsigned ab = f2u(fabsf(xk[i]));
      unsigned code = (unsigned)(15 - 4 * i) - (unsigned)l4;
      unsigned key = act ? ((ab & 0xFFFFFFE0u) | 0x10u | code) : 0u;
      kmax = key > kmax ? key : kmax;
    }
    kmax = dpp_maxu<0xB1>(kmax);   // quad_perm [1,0,3,2]
    kmax = dpp_maxu<0x4E>(kmax);   // quad_perm [2,3,0,1]
    const int p = 15 - (int)(kmax & 0xFu);
    const bool pb0 = (p & 4) != 0;   // owner row-slot bit0
    const bool pb1 = (p & 8) != 0;   // owner row-slot bit1
    const int bidx = lbase | ((p & 3) << 2);

    float s01 = pb0 ? XW(1, k) : XW(0, k);
    float s23 = pb0 ? XW(3, k) : XW(2, k);
    float piv = bperm_f(bidx, pb1 ? s23 : s01);

    int e; float mant = frexpf(piv, &e);
    prodm *= mant; esum += e;
    par ^= __popc(used & (0xFFFFFFFFu << (p + 1))) & 1;  // inversion parity
    used |= 1u << p;

    float rp = (piv != 0.0f) ? (1.0f / piv) : 0.0f;   // IEEE divide

    f32x2 mf[4];
    #pragma unroll
    for (int i = 0; i < 4; i++) {
      bool act = ((used >> (l4 + 4 * i)) & 1u) == 0u;  // post-update mask (owner frozen)
      float f = act ? xk[i] * rp : 0.0f;
      mf[i][0] = -f; mf[i][1] = -f;
    }
    #pragma unroll
    for (int jp = (k + 1) >> 1; jp < 8; jp++) {
      float a01 = pb0 ? XW(1, 2 * jp) : XW(0, 2 * jp);
      float a23 = pb0 ? XW(3, 2 * jp) : XW(2, 2 * jp);
      float t0 = bperm_f(bidx, pb1 ? a23 : a01);
      float b01 = pb0 ? XW(1, 2 * jp + 1) : XW(0, 2 * jp + 1);
      float b23 = pb0 ? XW(3, 2 * jp + 1) : XW(2, 2 * jp + 1);
      float t1 = bperm_f(bidx, pb1 ? b23 : b01);
      f32x2 tp; tp[0] = t0; tp[1] = t1;
      #pragma unroll
      for (int i = 0; i < 4; i++)
        xp[i][jp] = __builtin_elementwise_fma(tp, mf[i], xp[i][jp]);
    }
  }
  if (l4 == 0) {
    float la = (__log2f(fabsf(prodm)) + (float)esum) * 0.6931471805599453f;
    int neg = (prodm < 0.0f) ? 1 : 0;
    float sg = (prodm == 0.0f) ? 0.0f : (((neg ^ par) != 0) ? -1.0f : 1.0f);
    long long b = b0 + gm;
    out[b] = sg;
    out[(long long)B + b] = la;
  }
  #undef XW
}

extern "C" void kernel_launch(void* const* d_in, const int* in_sizes, int n_in,
                              void* d_out, int out_size, void* d_ws, size_t ws_size,
                              hipStream_t stream) {
  const float* occ  = (const float*)d_in[0];
  const float* Wg   = (const float*)d_in[1];
  const float* bias = (const float*)d_in[2];
  float* out = (float*)d_out;
  const int B = in_sizes[0] / NE;          // 262144
  unsigned short* wh = (unsigned short*)d_ws;
  unsigned short* wm = wh + NE * RR;
  unsigned short* wl = wm + NE * RR;       // 196608 B total in d_ws

  hipLaunchKernelGGL(wsplit3_kernel, dim3(NE * RR / 256), dim3(256), 0, stream,
                     Wg, wh, wm, wl);
  hipLaunchKernelGGL(jastrow_mfma, dim3(B / MT), dim3(256), 0, stream,
                     occ, wh, wm, wl, bias, out, B);
}